// Round 1
// baseline (315.547 us; speedup 1.0000x reference)
//
#include <hip/hip_runtime.h>

// new_emb[n,d] = curr_emb[n,0,d] + sum_k alpha[n,k] * msg[n,k,d]
// N=100000, K=32, D=128, fp32. Pure HBM-streaming kernel.

#define N_ROWS 100000
#define K_DIM 32
#define D_DIM 128

__global__ __launch_bounds__(256) void Aggregator_32959579030024_kernel(
    const float* __restrict__ curr_emb,   // [N,1,D]
    const float* __restrict__ alpha,      // [N,K,1]
    const float* __restrict__ msg,        // [N,K,D]
    float* __restrict__ out,              // [N,D]
    int n_total) {
  const int tid = threadIdx.x;
  const int n = blockIdx.x * 8 + (tid >> 5);   // 8 rows per 256-thread block
  if (n >= n_total) return;

  const int c = tid & 31;                      // float4 index within row: 0..31

  // Accumulator starts at curr_emb row
  float4 acc = reinterpret_cast<const float4*>(curr_emb + (size_t)n * D_DIM)[c];

  const float*  a    = alpha + (size_t)n * K_DIM;
  const float4* m4   = reinterpret_cast<const float4*>(msg + (size_t)n * K_DIM * D_DIM);

  #pragma unroll 8
  for (int k = 0; k < K_DIM; ++k) {
    const float  av = a[k];                    // broadcast across 32-lane group
    const float4 mv = m4[(size_t)k * 32 + c];  // coalesced 512B per 32-lane group
    acc.x += av * mv.x;
    acc.y += av * mv.y;
    acc.z += av * mv.z;
    acc.w += av * mv.w;
  }

  reinterpret_cast<float4*>(out + (size_t)n * D_DIM)[c] = acc;
}

extern "C" void kernel_launch(void* const* d_in, const int* in_sizes, int n_in,
                              void* d_out, int out_size, void* d_ws, size_t ws_size,
                              hipStream_t stream) {
  const float* curr_emb = (const float*)d_in[0];
  const float* alpha    = (const float*)d_in[1];
  const float* msg      = (const float*)d_in[2];
  float* out            = (float*)d_out;

  const int n_total = in_sizes[0] / D_DIM;     // N = 100000
  const int blocks  = (n_total + 7) / 8;       // 12500

  Aggregator_32959579030024_kernel<<<blocks, 256, 0, stream>>>(
      curr_emb, alpha, msg, out, n_total);
}

// Round 3
// 270.072 us; speedup vs baseline: 1.1684x; 1.1684x over previous
//
#include <hip/hip_runtime.h>

// new_emb[n,d] = curr_emb[n,0,d] + sum_k alpha[n,k] * msg[n,k,d]
// N=100000, K=32, D=128, fp32. Pure HBM-streaming kernel.
// 8 rows per 256-thread block; 32 lanes x f32x4 cover one D=128 row.

#define K_DIM 32
#define D_DIM 128

typedef float f32x4 __attribute__((ext_vector_type(4)));   // true vector type:
// __builtin_nontemporal_load/store accept it (HIP_vector_type float4 is a class, rejected)

__global__ __launch_bounds__(256) void Aggregator_32959579030024_kernel(
    const float* __restrict__ curr_emb,   // [N,1,D]
    const float* __restrict__ alpha,      // [N,K,1]
    const float* __restrict__ msg,        // [N,K,D]
    float* __restrict__ out,              // [N,D]
    int n_total) {
  const int tid = threadIdx.x;
  const int n = blockIdx.x * 8 + (tid >> 5);   // 8 rows per block (100000 % 8 == 0)
  if (n >= n_total) return;

  const int c = tid & 31;                      // f32x4 slot within row

  // ---- Preload the 32 alphas of this row into registers (statically indexed).
  // All 32 lanes of the group load the same 128B -> coalescer broadcast, cheap.
  const f32x4* a4 = reinterpret_cast<const f32x4*>(alpha + (size_t)n * K_DIM);
  float av[K_DIM];
  #pragma unroll
  for (int i = 0; i < 8; ++i) {
    const f32x4 t = a4[i];
    av[4 * i + 0] = t.x;
    av[4 * i + 1] = t.y;
    av[4 * i + 2] = t.z;
    av[4 * i + 3] = t.w;
  }

  f32x4 acc = reinterpret_cast<const f32x4*>(curr_emb + (size_t)n * D_DIM)[c];

  const f32x4* m4 = reinterpret_cast<const f32x4*>(msg + (size_t)n * K_DIM * D_DIM);

  // ---- K loop: 4 chunks of 8 nontemporal f32x4 loads in flight, then FMAs.
  #pragma unroll
  for (int kk = 0; kk < 4; ++kk) {
    f32x4 mv[8];
    #pragma unroll
    for (int j = 0; j < 8; ++j) {
      mv[j] = __builtin_nontemporal_load(&m4[(size_t)(kk * 8 + j) * 32 + c]);
    }
    #pragma unroll
    for (int j = 0; j < 8; ++j) {
      const float a = av[kk * 8 + j];          // compile-time index after unroll
      acc += a * mv[j];                        // vector FMA
    }
  }

  f32x4* o = reinterpret_cast<f32x4*>(out + (size_t)n * D_DIM);
  __builtin_nontemporal_store(acc, &o[c]);
}

extern "C" void kernel_launch(void* const* d_in, const int* in_sizes, int n_in,
                              void* d_out, int out_size, void* d_ws, size_t ws_size,
                              hipStream_t stream) {
  const float* curr_emb = (const float*)d_in[0];
  const float* alpha    = (const float*)d_in[1];
  const float* msg      = (const float*)d_in[2];
  float* out            = (float*)d_out;

  const int n_total = in_sizes[0] / D_DIM;     // N = 100000
  const int blocks  = (n_total + 7) / 8;       // 12500

  Aggregator_32959579030024_kernel<<<blocks, 256, 0, stream>>>(
      curr_emb, alpha, msg, out, n_total);
}